// Round 12
// baseline (470.190 us; speedup 1.0000x reference)
//
#include <hip/hip_runtime.h>

#define H 64
#define NUM_GRAPHS 64
#define BSHIFT 8
#define BSIZE 256            // nodes per bucket
#define MAXNB 512            // supports N <= 131072
#define CHUNK 8192           // edges per partition block
#define BKT 9216             // fixed bucket capacity (avg ~8184 + 11 sigma)
#define PADE 8               // row-start alignment (positions only, no fill)
#define CSRB (BKT + BSIZE * PADE)   // per-bucket csr region

typedef unsigned int uint;
typedef unsigned short ushort;
typedef __attribute__((ext_vector_type(4))) float f32x4;
typedef __attribute__((ext_vector_type(8))) short short8;

__device__ __forceinline__ float bf2f(ushort u) {
    return __uint_as_float(((uint)u) << 16);
}
__device__ __forceinline__ ushort f2bf(float f) {   // RNE
    uint b = __float_as_uint(f);
    b += 0x7FFFu + ((b >> 16) & 1u);
    return (ushort)(b >> 16);
}

// ---------------------------------------------------------------------------
__global__ void init_kernel(int* __restrict__ bucketCur, int NB) {
    int i = blockIdx.x * 256 + threadIdx.x;
    if (i < NB) bucketCur[i] = i * BKT;
}

// A: partition edges into fixed bucket regions with LDS staging (coalesced
// global writes). bucketCur[b] pre-initialized to b*BKT.
__global__ __launch_bounds__(1024) void part_kernel(const int* __restrict__ src,
        const int* __restrict__ dst, const float* __restrict__ w,
        int* __restrict__ bucketCur, int2* __restrict__ bucketed, int E, int NB) {
    __shared__ int h[MAXNB];
    __shared__ int basev[MAXNB];
    __shared__ int lbase[MAXNB + 1];
    __shared__ int s[512];
    __shared__ int2 stage[CHUNK];      // 64 KB
    int tid = threadIdx.x;
    for (int i = tid; i < NB; i += 1024) h[i] = 0;
    __syncthreads();
    int cbase = blockIdx.x * CHUNK;
    int cend = min(cbase + CHUNK, E);
    for (int e = cbase + tid; e < cend; e += 1024)
        atomicAdd(&h[dst[e] >> BSHIFT], 1);
    __syncthreads();
    for (int i = tid; i < NB; i += 1024) {
        int c = h[i];
        basev[i] = c ? atomicAdd(&bucketCur[i], c) : 0;
    }
    // exclusive scan of h -> lbase (LDS staging layout)
    if (tid < 512) s[tid] = (tid < NB) ? h[tid] : 0;
    __syncthreads();
    for (int off = 1; off < 512; off <<= 1) {
        int t = (tid < 512 && tid >= off) ? s[tid - off] : 0;
        __syncthreads();
        if (tid < 512) s[tid] += t;
        __syncthreads();
    }
    if (tid < NB) lbase[tid + 1] = s[tid];
    if (tid == 0) lbase[0] = 0;
    __syncthreads();
    for (int i = tid; i < NB; i += 1024) h[i] = 0;   // reuse as local cursor
    __syncthreads();
    for (int e = cbase + tid; e < cend; e += 1024) {
        int d = dst[e];
        int b = d >> BSHIFT;
        int slot = atomicAdd(&h[b], 1);
        stage[lbase[b] + slot] =
            make_int2(((d & (BSIZE - 1)) << 17) | src[e], __float_as_int(w[e]));
    }
    __syncthreads();
    // coalesced copy: wave per bucket, contiguous runs; guard region overflow
    int lane = tid & 63, wv = tid >> 6;              // 16 waves
    for (int b = wv; b < NB; b += 16) {
        int lb = lbase[b], cnt = lbase[b + 1] - lb, gb = basev[b];
        int lim = (b + 1) * BKT;
        for (int k = lane; k < cnt; k += 64)
            if (gb + k < lim) bucketed[gb + k] = stage[lb + k];
    }
}

// B: per-bucket counting sort -> csr rows (src<<15 | bf16w), 8-aligned row
// starts + rowinfo{base, realLen} + degw. No pad fill (tails read pv=0).
__global__ __launch_bounds__(512) void bsort_kernel(const int* __restrict__ bucketCur,
        const int2* __restrict__ bucketed, uint* __restrict__ csr,
        int2* __restrict__ rowinfo, float* __restrict__ degw, int N) {
    __shared__ int cnt[BSIZE];
    __shared__ int pos[BSIZE];
    __shared__ int cur[BSIZE];
    __shared__ float wsum[BSIZE];
    int b = blockIdx.x;
    int tid = threadIdx.x;
    int nodeBase = b << BSHIFT;
    int nNodes = min(BSIZE, N - nodeBase);
    if (tid < BSIZE) { cnt[tid] = 0; wsum[tid] = 0.f; }
    __syncthreads();
    int ebeg = b * BKT;
    int eend = min(bucketCur[b], ebeg + BKT);
    for (int e = ebeg + tid; e < eend; e += 512)
        atomicAdd(&cnt[bucketed[e].x >> 17], 1);
    __syncthreads();
    int pc = 0;
    if (tid < BSIZE) { pc = (cnt[tid] + PADE - 1) & ~(PADE - 1); pos[tid] = pc; }
    __syncthreads();
    for (int off = 1; off < BSIZE; off <<= 1) {      // inclusive scan of aligned counts
        int t = (tid < BSIZE && tid >= off) ? pos[tid - off] : 0;
        __syncthreads();
        if (tid < BSIZE) pos[tid] += t;
        __syncthreads();
    }
    int csrBase = b * CSRB;
    if (tid < BSIZE) {
        int excl = pos[tid] - pc;
        cur[tid] = excl;
        if (tid < nNodes) rowinfo[nodeBase + tid] = make_int2(csrBase + excl, cnt[tid]);
    }
    __syncthreads();
    for (int e = ebeg + tid; e < eend; e += 512) {
        int2 v = bucketed[e];
        int dl = v.x >> 17;
        int slot = atomicAdd(&cur[dl], 1);
        uint wb = (uint)v.y;                          // fp32 bits, sign=0 (w in [0,1))
        wb += 0x7FFFu + ((wb >> 16) & 1u);            // RNE to bf16
        uint w15 = (wb >> 16) & 0x7FFFu;
        csr[csrBase + slot] = (((uint)(v.x & 0x1FFFF)) << 15) | w15;
        atomicAdd(&wsum[dl], __uint_as_float(w15 << 16));
    }
    __syncthreads();
    if (tid < nNodes) degw[nodeBase + tid] = wsum[tid];
}

// ---------------------------------------------------------------------------
// layer 1 collapses: x1[i,c] = relu(degw[i]*W1[c]+b1[c]); channel-BLOCKED out
__global__ void layer1_kernel(const float* __restrict__ degw, const float* __restrict__ W1,
                              const float* __restrict__ b1, ushort* __restrict__ outB, int N) {
    int gid = blockIdx.x * 256 + threadIdx.x;   // over N*16
    if (gid >= N * 16) return;
    int i = gid >> 4, c4 = (gid & 15) * 4;
    float d = degw[i];
    uint lo = (uint)f2bf(fmaxf(d * W1[c4 + 0] + b1[c4 + 0], 0.f))
            | ((uint)f2bf(fmaxf(d * W1[c4 + 1] + b1[c4 + 1], 0.f)) << 16);
    uint hi = (uint)f2bf(fmaxf(d * W1[c4 + 2] + b1[c4 + 2], 0.f))
            | ((uint)f2bf(fmaxf(d * W1[c4 + 3] + b1[c4 + 3], 0.f)) << 16);
    size_t off = (size_t)(c4 >> 5) * N * 32 + ((size_t)i << 5) + (c4 & 31);
    *reinterpret_cast<uint2*>(outB + off) = make_uint2(lo, hi);
}

// per-graph node counts (for mean-pool divisor)
__global__ void count_kernel(const int* __restrict__ batch, float* __restrict__ gcnt, int N) {
    __shared__ int bins[NUM_GRAPHS];
    int tid = threadIdx.x;
    if (tid < NUM_GRAPHS) bins[tid] = 0;
    __syncthreads();
    int node = blockIdx.x * 256 + tid;
    if (node < N) atomicAdd(&bins[batch[node]], 1);
    __syncthreads();
    if (tid < NUM_GRAPHS && bins[tid])
        unsafeAtomicAdd(&gcnt[tid], (float)bins[tid]);
}

// Pass A: XCD-sliced aggregation over channel-BLOCKED features.
// slice = (blockIdx&7)>>2 -> XCDs 0-3 own block 0 (6.4MB), XCDs 4-7 block 1.
// Wave = 2 rows (half-wave each) x 32 channels; R6-style LDS packet cache,
// guarded full unroll (8 gathers/group in flight), dual accumulators.
__global__ __launch_bounds__(256) void aggA_kernel(const int2* __restrict__ rowinfo,
        const uint* __restrict__ csr, const ushort* __restrict__ xB,
        ushort* __restrict__ aggB, int N, int nchunk) {
    __shared__ uint pc[4][64];
    int b = blockIdx.x;
    int r8 = b & 7;
    int slice = r8 >> 2;
    int chunk = (b >> 3) * 4 + (r8 & 3);
    if (chunk >= nchunk) return;
    int rowbase = chunk * 16;
    int tid = threadIdx.x, lane = tid & 63, wid = tid >> 6;
    int hi = lane >> 5;                  // half-wave id = which row
    int lch = lane & 31;                 // channel within slice
    const char* xsb = (const char*)(xB + (size_t)slice * N * 32) + (lch << 1);
    ushort* asb = aggB + (size_t)slice * N * 32 + lch;
    int pcb = hi << 5;                   // packet-cache half base
#pragma unroll 1
    for (int p = 0; p < 2; ++p) {
        int row = rowbase + wid * 4 + p * 2 + hi;
        int rr = min(row, N - 1);
        int2 ri = rowinfo[rr];
        int beg = ri.x;
        int len = (row < N) ? ri.y : 0;
        int lenm = max(len, __shfl_xor(len, 32));   // wave-uniform bound
        float a0 = 0.f, a1 = 0.f;
#pragma unroll 1
        for (int ck = 0; ck < lenm; ck += 32) {
            int idx = ck + lch;
            uint pv = (idx < len) ? __builtin_nontemporal_load(csr + beg + idx) : 0u;
            pc[wid][pcb + lch] = pv;                // same-wave write->read
            int rem = len - ck;
#pragma unroll
            for (int g = 0; g < 4; ++g) {
                if (g * 8 < rem) {
#pragma unroll
                    for (int j = 0; j < 8; ++j) {
                        uint pp = pc[wid][pcb + g * 8 + j];
                        float wf = __uint_as_float((pp & 0x7FFFu) << 16);
                        ushort u = *reinterpret_cast<const ushort*>(
                                       xsb + ((size_t)(pp >> 15) << 6));
                        if (g & 1) a1 = fmaf(wf, bf2f(u), a1);
                        else       a0 = fmaf(wf, bf2f(u), a0);
                    }
                }
            }
        }
        if (row < N) asb[(size_t)row << 5] = f2bf(a0 + a1);
    }
}

// Pass B: out = relu(agg @ W + b) via MFMA; blocked A reads/out writes.
// LAST: feed graph mean-pool numerator directly (LDS bins, one flush/block).
template<bool LAST, int TILES>
__global__ __launch_bounds__(256) void matB_kernel(const ushort* __restrict__ aggB,
        const float* __restrict__ W, const float* __restrict__ bvec,
        ushort* __restrict__ outB, const int* __restrict__ batch,
        const float* __restrict__ linw, float* __restrict__ gsum, int N) {
    __shared__ alignas(16) ushort Wt[64][72];   // Wt[c][k] = bf16(W[k][c])
    __shared__ float gbins[NUM_GRAPHS];
    int tid = threadIdx.x;
    for (int i = tid; i < 64 * 64; i += 256) {
        int k = i >> 6, c = i & 63;
        Wt[c][k] = f2bf(W[i]);
    }
    if (LAST && tid < NUM_GRAPHS) gbins[tid] = 0.f;
    __syncthreads();
    int lane = tid & 63, wid = tid >> 6;
    int cl = lane & 15, kg = lane >> 4;
    int c0 = wid * 16;
    int cc = c0 + cl;
    size_t oblk = (size_t)(cc >> 5) * N * 32;
    for (int t = 0; t < TILES; ++t) {
        int rowbase = (blockIdx.x * TILES + t) * 16;
        if (rowbase >= N) break;
        const ushort* ap0 = aggB + (((size_t)(rowbase + cl)) << 5) + kg * 8;
        short8 a0v = *reinterpret_cast<const short8*>(ap0);                   // k 0-31
        short8 a1v = *reinterpret_cast<const short8*>(ap0 + (size_t)N * 32);  // k 32-63
        short8 bb0 = *reinterpret_cast<const short8*>(&Wt[cc][kg * 8]);
        short8 bb1 = *reinterpret_cast<const short8*>(&Wt[cc][32 + kg * 8]);
        f32x4 acc = {0.f, 0.f, 0.f, 0.f};
        acc = __builtin_amdgcn_mfma_f32_16x16x32_bf16(a0v, bb0, acc, 0, 0, 0);
        acc = __builtin_amdgcn_mfma_f32_16x16x32_bf16(a1v, bb1, acc, 0, 0, 0);
        float bias = bvec[cc];
        float lw = LAST ? linw[cc] : 0.f;
#pragma unroll
        for (int j = 0; j < 4; ++j) {                  // C: col=lane&15, row=kg*4+j
            int r = rowbase + kg * 4 + j;
            if (r < N) {
                float v = fmaxf(acc[j] + bias, 0.f);
                if (!LAST)
                    __builtin_nontemporal_store(f2bf(v),
                        outB + oblk + ((size_t)r << 5) + (cc & 31));
                else
                    atomicAdd(&gbins[batch[r]], v * lw);
            }
        }
    }
    if (LAST) {
        __syncthreads();
        if (tid < NUM_GRAPHS) unsafeAtomicAdd(&gsum[tid], gbins[tid]);
    }
}

__global__ void final_kernel(const float* __restrict__ gsum, const float* __restrict__ gcnt,
                             const float* __restrict__ lin_b, float* __restrict__ out) {
    int g = threadIdx.x;
    if (g < NUM_GRAPHS) out[g] = gsum[g] / fmaxf(gcnt[g], 1.f) + lin_b[0];
}

extern "C" void kernel_launch(void* const* d_in, const int* in_sizes, int n_in,
                              void* d_out, int out_size, void* d_ws, size_t ws_size,
                              hipStream_t stream) {
    const int*   edge_index = (const int*)d_in[0];
    const float* ew    = (const float*)d_in[1];
    const int*   batch = (const int*)d_in[2];
    const float* W1    = (const float*)d_in[4];
    const float* b1    = (const float*)d_in[5];
    const float* Wl[4] = {(const float*)d_in[6], (const float*)d_in[8],
                          (const float*)d_in[10], (const float*)d_in[12]};
    const float* bl[4] = {(const float*)d_in[7], (const float*)d_in[9],
                          (const float*)d_in[11], (const float*)d_in[13]};
    const float* linw  = (const float*)d_in[14];
    const float* linb  = (const float*)d_in[15];

    const int E = in_sizes[1];
    const int N = in_sizes[2];
    const int* src = edge_index;
    const int* dst = edge_index + E;
    const int NB = (N + BSIZE - 1) >> BSHIFT;

    // workspace: [bucketed | bufA,bufB,bufC] union, then csr, then tail
    char* base = (char*)d_ws;
    size_t featPad = (((size_t)(N + 16) * H * 2) + 255) & ~(size_t)255;
    size_t bktBytes = (((size_t)NB * BKT * 8) + 255) & ~(size_t)255;
    size_t span = 3 * featPad > bktBytes ? 3 * featPad : bktBytes;
    ushort* bufA = (ushort*)base;
    ushort* bufB = (ushort*)(base + featPad);
    ushort* bufC = (ushort*)(base + 2 * featPad);        // agg
    int2* bucketed = (int2*)base;                        // alias (build only)
    uint* csr = (uint*)(base + span);
    size_t csrBytes = (((size_t)NB * CSRB * 4) + 255) & ~(size_t)255;
    char* tail = base + span + csrBytes;
    int2* rowinfo   = (int2*)tail;                       // N
    int* bucketCur  = (int*)(rowinfo + N);               // MAXNB
    float* gsum     = (float*)(bucketCur + MAXNB);       // 64
    float* gcnt     = gsum + NUM_GRAPHS;                 // 64
    float* degw     = gcnt + NUM_GRAPHS;                 // N

    const int chunks = (E + CHUNK - 1) / CHUNK;

    // ---- CSR build: fixed bucket regions (no global histogram/scan pass)
    init_kernel<<<(NB + 255) / 256, 256, 0, stream>>>(bucketCur, NB);
    hipMemsetAsync(gsum, 0, 2 * NUM_GRAPHS * sizeof(float), stream);
    part_kernel<<<chunks, 1024, 0, stream>>>(src, dst, ew, bucketCur, bucketed, E, NB);
    bsort_kernel<<<NB, 512, 0, stream>>>(bucketCur, bucketed, csr, rowinfo, degw, N);

    // ---- layer 1 (collapsed: all-ones input through 1->64 linear)
    layer1_kernel<<<(N * 16 + 255) / 256, 256, 0, stream>>>(degw, W1, b1, bufA, N);
    count_kernel<<<(N + 255) / 256, 256, 0, stream>>>(batch, gcnt, N);

    // ---- layers 2..5: Pass A (XCD-sliced blocked gather) + Pass B (MFMA)
    const int nchunk = (N + 15) / 16;
    const int gridA = 8 * ((nchunk + 3) / 4);
    const int nt16 = (N + 15) / 16;
    ushort* xin = bufA;
    ushort* xout = bufB;
    for (int l = 0; l < 3; ++l) {
        aggA_kernel<<<gridA, 256, 0, stream>>>(rowinfo, csr, xin, bufC, N, nchunk);
        matB_kernel<false, 2><<<(nt16 + 1) / 2, 256, 0, stream>>>(bufC, Wl[l], bl[l],
                xout, batch, linw, gsum, N);
        ushort* t = xin; xin = xout; xout = t;
    }
    // layer 5: Pass B fused with graph mean-pool numerator
    aggA_kernel<<<gridA, 256, 0, stream>>>(rowinfo, csr, xin, bufC, N, nchunk);
    matB_kernel<true, 8><<<(nt16 + 7) / 8, 256, 0, stream>>>(bufC, Wl[3], bl[3],
            xout, batch, linw, gsum, N);

    final_kernel<<<1, 64, 0, stream>>>(gsum, gcnt, linb, (float*)d_out);
}

// Round 13
// 460.197 us; speedup vs baseline: 1.0217x; 1.0217x over previous
//
#include <hip/hip_runtime.h>

#define H 64
#define NUM_GRAPHS 64
#define BSHIFT 8
#define BSIZE 256            // nodes per bucket
#define MAXNB 512            // supports N <= 131072
#define CHUNK 8192           // edges per partition block
#define BKT 9216             // fixed bucket capacity (avg ~8184 + 11 sigma)
#define PADE 8               // row-start alignment (positions only, no fill)
#define CSRB (BKT + BSIZE * PADE)   // per-bucket csr region
#define RPB 16               // rows per block in layer kernel

typedef unsigned int uint;
typedef unsigned short ushort;
typedef __attribute__((ext_vector_type(4))) float f32x4;
typedef __attribute__((ext_vector_type(8))) short short8;

__device__ __forceinline__ float bf2f(ushort u) {
    return __uint_as_float(((uint)u) << 16);
}
__device__ __forceinline__ ushort f2bf(float f) {   // RNE
    uint b = __float_as_uint(f);
    b += 0x7FFFu + ((b >> 16) & 1u);
    return (ushort)(b >> 16);
}

// ---------------------------------------------------------------------------
__global__ void init_kernel(int* __restrict__ bucketCur, int NB) {
    int i = blockIdx.x * 256 + threadIdx.x;
    if (i < NB) bucketCur[i] = i * BKT;
}

// A: partition edges into fixed bucket regions with LDS staging (coalesced
// global writes). bucketCur[b] pre-initialized to b*BKT.
__global__ __launch_bounds__(1024) void part_kernel(const int* __restrict__ src,
        const int* __restrict__ dst, const float* __restrict__ w,
        int* __restrict__ bucketCur, int2* __restrict__ bucketed, int E, int NB) {
    __shared__ int h[MAXNB];
    __shared__ int basev[MAXNB];
    __shared__ int lbase[MAXNB + 1];
    __shared__ int s[512];
    __shared__ int2 stage[CHUNK];      // 64 KB
    int tid = threadIdx.x;
    for (int i = tid; i < NB; i += 1024) h[i] = 0;
    __syncthreads();
    int cbase = blockIdx.x * CHUNK;
    int cend = min(cbase + CHUNK, E);
    for (int e = cbase + tid; e < cend; e += 1024)
        atomicAdd(&h[dst[e] >> BSHIFT], 1);
    __syncthreads();
    for (int i = tid; i < NB; i += 1024) {
        int c = h[i];
        basev[i] = c ? atomicAdd(&bucketCur[i], c) : 0;
    }
    // exclusive scan of h -> lbase (LDS staging layout)
    if (tid < 512) s[tid] = (tid < NB) ? h[tid] : 0;
    __syncthreads();
    for (int off = 1; off < 512; off <<= 1) {
        int t = (tid < 512 && tid >= off) ? s[tid - off] : 0;
        __syncthreads();
        if (tid < 512) s[tid] += t;
        __syncthreads();
    }
    if (tid < NB) lbase[tid + 1] = s[tid];
    if (tid == 0) lbase[0] = 0;
    __syncthreads();
    for (int i = tid; i < NB; i += 1024) h[i] = 0;   // reuse as local cursor
    __syncthreads();
    for (int e = cbase + tid; e < cend; e += 1024) {
        int d = dst[e];
        int b = d >> BSHIFT;
        int slot = atomicAdd(&h[b], 1);
        stage[lbase[b] + slot] =
            make_int2(((d & (BSIZE - 1)) << 17) | src[e], __float_as_int(w[e]));
    }
    __syncthreads();
    // coalesced copy: wave per bucket, contiguous runs; guard region overflow
    int lane = tid & 63, wv = tid >> 6;              // 16 waves
    for (int b = wv; b < NB; b += 16) {
        int lb = lbase[b], cnt = lbase[b + 1] - lb, gb = basev[b];
        int lim = (b + 1) * BKT;
        for (int k = lane; k < cnt; k += 64)
            if (gb + k < lim) bucketed[gb + k] = stage[lb + k];
    }
}

// B: per-bucket counting sort -> csr rows (src<<15 | bf16w), 8-aligned row
// starts + rowinfo{base, realLen} + degw. No pad fill (tails read pv=0).
__global__ __launch_bounds__(512) void bsort_kernel(const int* __restrict__ bucketCur,
        const int2* __restrict__ bucketed, uint* __restrict__ csr,
        int2* __restrict__ rowinfo, float* __restrict__ degw, int N) {
    __shared__ int cnt[BSIZE];
    __shared__ int pos[BSIZE];
    __shared__ int cur[BSIZE];
    __shared__ float wsum[BSIZE];
    int b = blockIdx.x;
    int tid = threadIdx.x;
    int nodeBase = b << BSHIFT;
    int nNodes = min(BSIZE, N - nodeBase);
    if (tid < BSIZE) { cnt[tid] = 0; wsum[tid] = 0.f; }
    __syncthreads();
    int ebeg = b * BKT;
    int eend = min(bucketCur[b], ebeg + BKT);
    for (int e = ebeg + tid; e < eend; e += 512)
        atomicAdd(&cnt[bucketed[e].x >> 17], 1);
    __syncthreads();
    int pc = 0;
    if (tid < BSIZE) { pc = (cnt[tid] + PADE - 1) & ~(PADE - 1); pos[tid] = pc; }
    __syncthreads();
    for (int off = 1; off < BSIZE; off <<= 1) {      // inclusive scan of aligned counts
        int t = (tid < BSIZE && tid >= off) ? pos[tid - off] : 0;
        __syncthreads();
        if (tid < BSIZE) pos[tid] += t;
        __syncthreads();
    }
    int csrBase = b * CSRB;
    if (tid < BSIZE) {
        int excl = pos[tid] - pc;
        cur[tid] = excl;
        if (tid < nNodes) rowinfo[nodeBase + tid] = make_int2(csrBase + excl, cnt[tid]);
    }
    __syncthreads();
    for (int e = ebeg + tid; e < eend; e += 512) {
        int2 v = bucketed[e];
        int dl = v.x >> 17;
        int slot = atomicAdd(&cur[dl], 1);
        uint wb = (uint)v.y;                          // fp32 bits, sign=0 (w in [0,1))
        wb += 0x7FFFu + ((wb >> 16) & 1u);            // RNE to bf16
        uint w15 = (wb >> 16) & 0x7FFFu;
        csr[csrBase + slot] = (((uint)(v.x & 0x1FFFF)) << 15) | w15;
        atomicAdd(&wsum[dl], __uint_as_float(w15 << 16));
    }
    __syncthreads();
    if (tid < nNodes) degw[nodeBase + tid] = wsum[tid];
}

// ---------------------------------------------------------------------------
// layer 1 collapses: x1[i,c] = relu(degw[i]*W1[c]+b1[c]); 4 channels/thread
__global__ void layer1_kernel(const float* __restrict__ degw, const float* __restrict__ W1,
                              const float* __restrict__ b1, ushort* __restrict__ out, int N) {
    int gid = blockIdx.x * 256 + threadIdx.x;   // over N*16
    if (gid >= N * 16) return;
    int i = gid >> 4, c4 = (gid & 15) * 4;
    float d = degw[i];
    uint lo = (uint)f2bf(fmaxf(d * W1[c4 + 0] + b1[c4 + 0], 0.f))
            | ((uint)f2bf(fmaxf(d * W1[c4 + 1] + b1[c4 + 1], 0.f)) << 16);
    uint hi = (uint)f2bf(fmaxf(d * W1[c4 + 2] + b1[c4 + 2], 0.f))
            | ((uint)f2bf(fmaxf(d * W1[c4 + 3] + b1[c4 + 3], 0.f)) << 16);
    *reinterpret_cast<uint2*>(out + ((size_t)i << 6) + c4) = make_uint2(lo, hi);
}

// per-graph node counts (for mean-pool divisor)
__global__ void count_kernel(const int* __restrict__ batch, float* __restrict__ gcnt, int N) {
    __shared__ int bins[NUM_GRAPHS];
    int tid = threadIdx.x;
    if (tid < NUM_GRAPHS) bins[tid] = 0;
    __syncthreads();
    int node = blockIdx.x * 256 + tid;
    if (node < N) atomicAdd(&bins[batch[node]], 1);
    __syncthreads();
    if (tid < NUM_GRAPHS && bins[tid])
        unsafeAtomicAdd(&gcnt[tid], (float)bins[tid]);
}

// fused layer: out[d,:] = relu( (sum_e w_e * x[src_e,:]) @ W + b )
// R6 structure: wave per row, lane = channel, per-wave LDS packet cache.
// CHANGE vs R6: 16-edge groups with ZERO-PACKET padding (pads gather row 0
// with w=0) -> only 4 guard branches per 64-edge chunk, 16 gathers in
// flight, 4-way split accumulators. MFMA epilogue per 16-row tile.
// LAST: feed graph mean-pool numerator directly (LDS bins, one flush/block).
template<bool LAST>
__global__ __launch_bounds__(256) void layer_kernel(const int2* __restrict__ rowinfo,
        const uint* __restrict__ csr, const ushort* __restrict__ x,
        const float* __restrict__ W, const float* __restrict__ bvec,
        ushort* __restrict__ out, const int* __restrict__ batch,
        const float* __restrict__ linw, float* __restrict__ gsum, int N) {
    __shared__ alignas(16) ushort Wt[64][72];   // Wt[c][k] = bf16(W[k][c]), +8 pad
    __shared__ alignas(16) ushort AG[RPB][72];  // bf16 agg rows, +8 pad
    __shared__ uint pc[4][64];                  // per-wave CSR row cache
    __shared__ float gbins[NUM_GRAPHS];
    int tid = threadIdx.x;
    for (int i = tid; i < 64 * 64; i += 256) {  // stage W transposed as bf16
        int k = i >> 6, c = i & 63;
        Wt[c][k] = f2bf(W[i]);
    }
    if (LAST && tid < NUM_GRAPHS) gbins[tid] = 0.f;
    __syncthreads();
    int lane = tid & 63, wid = tid >> 6;
    int rowbase = blockIdx.x * RPB;
#pragma unroll 1
    for (int p = 0; p < 4; ++p) {
        int trow = wid * 4 + p;
        int row = rowbase + trow;
        float a0 = 0.f, a1 = 0.f, a2 = 0.f, a3 = 0.f;
        if (row < N) {
            int2 ri = rowinfo[row];              // wave-uniform
            int beg = ri.x, len = ri.y;
#pragma unroll 1
            for (int ck = 0; ck < len; ck += 64) {
                int idx = ck + lane;
                uint pv = (idx < len) ? __builtin_nontemporal_load(csr + beg + idx) : 0u;
                pc[wid][lane] = pv;              // same-wave write->read (pads = 0)
                int ng = (min(64, len - ck) + 15) >> 4;   // 16-edge groups: 1..4
#pragma unroll
                for (int g = 0; g < 4; ++g) {
                    if (g < ng) {
                        uint q0  = pc[wid][g * 16 + 0],  q1  = pc[wid][g * 16 + 1];
                        uint q2  = pc[wid][g * 16 + 2],  q3  = pc[wid][g * 16 + 3];
                        uint q4  = pc[wid][g * 16 + 4],  q5  = pc[wid][g * 16 + 5];
                        uint q6  = pc[wid][g * 16 + 6],  q7  = pc[wid][g * 16 + 7];
                        uint q8  = pc[wid][g * 16 + 8],  q9  = pc[wid][g * 16 + 9];
                        uint q10 = pc[wid][g * 16 + 10], q11 = pc[wid][g * 16 + 11];
                        uint q12 = pc[wid][g * 16 + 12], q13 = pc[wid][g * 16 + 13];
                        uint q14 = pc[wid][g * 16 + 14], q15 = pc[wid][g * 16 + 15];
                        // 16 independent gathers (zero packets hit row 0, w=0)
                        ushort u0  = x[(q0  >> 15) * H + lane];
                        ushort u1  = x[(q1  >> 15) * H + lane];
                        ushort u2  = x[(q2  >> 15) * H + lane];
                        ushort u3  = x[(q3  >> 15) * H + lane];
                        ushort u4  = x[(q4  >> 15) * H + lane];
                        ushort u5  = x[(q5  >> 15) * H + lane];
                        ushort u6  = x[(q6  >> 15) * H + lane];
                        ushort u7  = x[(q7  >> 15) * H + lane];
                        ushort u8  = x[(q8  >> 15) * H + lane];
                        ushort u9  = x[(q9  >> 15) * H + lane];
                        ushort u10 = x[(q10 >> 15) * H + lane];
                        ushort u11 = x[(q11 >> 15) * H + lane];
                        ushort u12 = x[(q12 >> 15) * H + lane];
                        ushort u13 = x[(q13 >> 15) * H + lane];
                        ushort u14 = x[(q14 >> 15) * H + lane];
                        ushort u15 = x[(q15 >> 15) * H + lane];
                        a0 = fmaf(__uint_as_float((q0  & 0x7FFFu) << 16), bf2f(u0),  a0);
                        a1 = fmaf(__uint_as_float((q1  & 0x7FFFu) << 16), bf2f(u1),  a1);
                        a2 = fmaf(__uint_as_float((q2  & 0x7FFFu) << 16), bf2f(u2),  a2);
                        a3 = fmaf(__uint_as_float((q3  & 0x7FFFu) << 16), bf2f(u3),  a3);
                        a0 = fmaf(__uint_as_float((q4  & 0x7FFFu) << 16), bf2f(u4),  a0);
                        a1 = fmaf(__uint_as_float((q5  & 0x7FFFu) << 16), bf2f(u5),  a1);
                        a2 = fmaf(__uint_as_float((q6  & 0x7FFFu) << 16), bf2f(u6),  a2);
                        a3 = fmaf(__uint_as_float((q7  & 0x7FFFu) << 16), bf2f(u7),  a3);
                        a0 = fmaf(__uint_as_float((q8  & 0x7FFFu) << 16), bf2f(u8),  a0);
                        a1 = fmaf(__uint_as_float((q9  & 0x7FFFu) << 16), bf2f(u9),  a1);
                        a2 = fmaf(__uint_as_float((q10 & 0x7FFFu) << 16), bf2f(u10), a2);
                        a3 = fmaf(__uint_as_float((q11 & 0x7FFFu) << 16), bf2f(u11), a3);
                        a0 = fmaf(__uint_as_float((q12 & 0x7FFFu) << 16), bf2f(u12), a0);
                        a1 = fmaf(__uint_as_float((q13 & 0x7FFFu) << 16), bf2f(u13), a1);
                        a2 = fmaf(__uint_as_float((q14 & 0x7FFFu) << 16), bf2f(u14), a2);
                        a3 = fmaf(__uint_as_float((q15 & 0x7FFFu) << 16), bf2f(u15), a3);
                    }
                }
            }
        }
        AG[trow][lane] = f2bf((a0 + a1) + (a2 + a3));  // same-wave write
    }
    __syncthreads();
    // MFMA epilogue: wave wid -> output cols [wid*16, wid*16+16)
    int cl = lane & 15, kg = lane >> 4;
    int c0 = wid * 16;
    short8 a0v = *reinterpret_cast<const short8*>(&AG[cl][kg * 8]);
    short8 a1v = *reinterpret_cast<const short8*>(&AG[cl][32 + kg * 8]);
    short8 bb0 = *reinterpret_cast<const short8*>(&Wt[c0 + cl][kg * 8]);
    short8 bb1 = *reinterpret_cast<const short8*>(&Wt[c0 + cl][32 + kg * 8]);
    f32x4 acc = {0.f, 0.f, 0.f, 0.f};
    acc = __builtin_amdgcn_mfma_f32_16x16x32_bf16(a0v, bb0, acc, 0, 0, 0);
    acc = __builtin_amdgcn_mfma_f32_16x16x32_bf16(a1v, bb1, acc, 0, 0, 0);
    float bias = bvec[c0 + cl];
    float lw = LAST ? linw[c0 + cl] : 0.f;
#pragma unroll
    for (int j = 0; j < 4; ++j) {                 // C: col=lane&15, row=kg*4+j
        int r = rowbase + kg * 4 + j;
        if (r < N) {
            float v = fmaxf(acc[j] + bias, 0.f);
            if (!LAST)
                __builtin_nontemporal_store(f2bf(v), out + ((size_t)r << 6) + c0 + cl);
            else
                atomicAdd(&gbins[batch[r]], v * lw);
        }
    }
    if (LAST) {
        __syncthreads();
        if (tid < NUM_GRAPHS) unsafeAtomicAdd(&gsum[tid], gbins[tid]);
    }
}

__global__ void final_kernel(const float* __restrict__ gsum, const float* __restrict__ gcnt,
                             const float* __restrict__ lin_b, float* __restrict__ out) {
    int g = threadIdx.x;
    if (g < NUM_GRAPHS) out[g] = gsum[g] / fmaxf(gcnt[g], 1.f) + lin_b[0];
}

extern "C" void kernel_launch(void* const* d_in, const int* in_sizes, int n_in,
                              void* d_out, int out_size, void* d_ws, size_t ws_size,
                              hipStream_t stream) {
    const int*   edge_index = (const int*)d_in[0];
    const float* ew    = (const float*)d_in[1];
    const int*   batch = (const int*)d_in[2];
    const float* W1    = (const float*)d_in[4];
    const float* b1    = (const float*)d_in[5];
    const float* Wl[4] = {(const float*)d_in[6], (const float*)d_in[8],
                          (const float*)d_in[10], (const float*)d_in[12]};
    const float* bl[4] = {(const float*)d_in[7], (const float*)d_in[9],
                          (const float*)d_in[11], (const float*)d_in[13]};
    const float* linw  = (const float*)d_in[14];
    const float* linb  = (const float*)d_in[15];

    const int E = in_sizes[1];
    const int N = in_sizes[2];
    const int* src = edge_index;
    const int* dst = edge_index + E;
    const int NB = (N + BSIZE - 1) >> BSHIFT;

    // workspace layout: [bucketed | bufA,bufB] union, then csr, then tail
    char* base = (char*)d_ws;
    size_t featPad = (((size_t)(N + 16) * H * 2) + 255) & ~(size_t)255;
    size_t bktBytes = (((size_t)NB * BKT * 8) + 255) & ~(size_t)255;
    size_t span = 2 * featPad > bktBytes ? 2 * featPad : bktBytes;
    ushort* bufA = (ushort*)base;
    ushort* bufB = (ushort*)(base + featPad);
    int2* bucketed = (int2*)base;                        // alias (build only)
    uint* csr = (uint*)(base + span);
    size_t csrBytes = (((size_t)NB * CSRB * 4) + 255) & ~(size_t)255;
    char* tail = base + span + csrBytes;
    int2* rowinfo   = (int2*)tail;                       // N
    int* bucketCur  = (int*)(rowinfo + N);               // MAXNB
    float* gsum     = (float*)(bucketCur + MAXNB);       // 64
    float* gcnt     = gsum + NUM_GRAPHS;                 // 64
    float* degw     = gcnt + NUM_GRAPHS;                 // N

    const int chunks = (E + CHUNK - 1) / CHUNK;

    // ---- CSR build: fixed bucket regions (no global histogram/scan pass)
    init_kernel<<<(NB + 255) / 256, 256, 0, stream>>>(bucketCur, NB);
    hipMemsetAsync(gsum, 0, 2 * NUM_GRAPHS * sizeof(float), stream);
    part_kernel<<<chunks, 1024, 0, stream>>>(src, dst, ew, bucketCur, bucketed, E, NB);
    bsort_kernel<<<NB, 512, 0, stream>>>(bucketCur, bucketed, csr, rowinfo, degw, N);

    // ---- layer 1 (collapsed: all-ones input through 1->64 linear)
    layer1_kernel<<<(N * 16 + 255) / 256, 256, 0, stream>>>(degw, W1, b1, bufA, N);
    count_kernel<<<(N + 255) / 256, 256, 0, stream>>>(batch, gcnt, N);

    // ---- layers 2..5 (fused gather + MFMA matvec + bias + relu)
    const int gridL = (N + RPB - 1) / RPB;
    ushort* xin = bufA;
    ushort* xout = bufB;
    for (int l = 0; l < 3; ++l) {
        layer_kernel<false><<<gridL, 256, 0, stream>>>(rowinfo, csr, xin, Wl[l], bl[l],
                xout, batch, linw, gsum, N);
        ushort* t = xin; xin = xout; xout = t;
    }
    // layer 5 fused with graph mean-pool numerator
    layer_kernel<true><<<gridL, 256, 0, stream>>>(rowinfo, csr, xin, Wl[3], bl[3],
            xout, batch, linw, gsum, N);

    final_kernel<<<1, 64, 0, stream>>>(gsum, gcnt, linb, (float*)d_out);
}